// Round 3
// baseline (197.957 us; speedup 1.0000x reference)
//
#include <hip/hip_runtime.h>
#include <hip/hip_fp16.h>
#include <math.h>

#define Nn 10000
#define Ee 320000
#define EE 330000        // E + N self loops
#define INF_ 256
#define NH 4
#define OUTC 128
#define F1 512
#define F2 512
#define SLOPE 0.2f
#define STRIDE 80        // ELL row capacity (max in-degree ~56; P(overflow)~1e-13)
#define LDK 40
#define NT 256
#define GRID 1024        // 4 blocks/CU x 256 CU == exact chip capacity at launch_bounds(256,4)
#define GT (GRID * NT)
#define MT 157           // ceil(Nn/64)
#define GEMM_TILES (MT * NH)      // 628
#define PASS_VB ((Nn / 16) * NH)  // 2500

static __device__ __forceinline__ float lrelu(float x) { return fmaxf(x, SLOPE * x); }

using frag_ab = __attribute__((ext_vector_type(8))) _Float16;
using frag_c  = __attribute__((ext_vector_type(4))) float;

struct Params {
    const float* x; const int* ei;
    const float* W1; const float* a_src1; const float* a_dst1; const float* b1;
    const float* W2; const float* a_src2; const float* a_dst2; const float* b2;
    float* out;
    int* counts; int* csr; int* bar;
    _Float16* hh; _Float16* aggh; _Float16* w1t; _Float16* w2t; _Float16* tmp;
    float* as1; float* ad1; float* as2; float* ad2;
};

// ---- device-scope grid barrier: per-phase arrival counter (zeroed by host memset) ----
// Release: AGENT-scope acq_rel RMW publishes all writes that happened-before it
// (block-local writes ordered in via the preceding __syncthreads).
// Acquire: AGENT-scope acquire load; visibility transfers to the block via the
// trailing __syncthreads. Cannot deadlock: grid == exact co-resident capacity.
static __device__ __forceinline__ void gbar(int* bar, int ph) {
    __syncthreads();
    if (threadIdx.x == 0) {
        __hip_atomic_fetch_add(&bar[ph], 1, __ATOMIC_ACQ_REL, __HIP_MEMORY_SCOPE_AGENT);
        while (__hip_atomic_load(&bar[ph], __ATOMIC_ACQUIRE, __HIP_MEMORY_SCOPE_AGENT) < GRID)
            __builtin_amdgcn_s_sleep(1);
    }
    __syncthreads();
}

// ---------------- phase 0: zero degree counters + W1/W2 -> fp16 transposes ----------------
static __device__ void prep0(const Params& p) {
    int gt = blockIdx.x * NT + threadIdx.x;
    for (int i = gt; i < Nn; i += GT) p.counts[i] = 0;
    for (int i = gt; i < F1 * INF_; i += GT) {         // w1t[n][k] = W1[k][n]
        int n = i >> 8, k = i & 255;
        p.w1t[i] = (_Float16)p.W1[(size_t)k * F1 + n];
    }
    for (int i = gt; i < F2 * F1; i += GT) {           // w2t[n][k] = W2[k][n]
        int n = i >> 9, k = i & 511;
        p.w2t[i] = (_Float16)p.W2[(size_t)k * F2 + n];
    }
}

// ---------------- ELL scatter (self-counting, no scan) ----------------
static __device__ void scatter_edges(const Params& p, int bi, int nb) {
    for (int e = bi * NT + threadIdx.x; e < EE; e += nb * NT) {
        int src, dst;
        if (e < Ee) { src = p.ei[e]; dst = p.ei[Ee + e]; }
        else        { src = e - Ee; dst = e - Ee; }
        int slot = atomicAdd(&p.counts[dst], 1);
        if (slot < STRIDE) p.csr[dst * STRIDE + slot] = src;
    }
}

// ---------------- MFMA fp16 GEMM tile + fused alpha dots (head-major alpha out) ----------------
// AF32: A is fp32 (layer 1 reads x directly, converts in-register during staging).
template <bool AF32>
static __device__ void gemm_tile(const _Float16* __restrict__ Ah,
                                 const float* __restrict__ Af,
                                 const _Float16* __restrict__ BT,
                                 _Float16* __restrict__ C,
                                 const float* __restrict__ a_src,
                                 const float* __restrict__ a_dst,
                                 float* __restrict__ as_out,
                                 float* __restrict__ ad_out,
                                 int K, int bmi, int head,
                                 _Float16* As, _Float16* Bs) {
    const int tid = threadIdx.x;
    const int wave = tid >> 6, lane = tid & 63;
    const int q = lane >> 4, ml = lane & 15;
    const int bm = bmi * 64, bn = head * 128;
    const int srow = tid >> 2, scol = (tid & 3) * 8;

    frag_c acc[8];
#pragma unroll
    for (int f = 0; f < 8; f++)
#pragma unroll
        for (int r = 0; r < 4; r++) acc[f][r] = 0.f;

    for (int k0 = 0; k0 < K; k0 += 32) {
        int gm = bm + srow;
        frag_ab av;
        if (gm < Nn) {
            if constexpr (AF32) {
                const float* Ap = Af + (size_t)gm * K + k0 + scol;
                float4 v0 = *(const float4*)Ap;
                float4 v1 = *(const float4*)(Ap + 4);
                av[0] = (_Float16)v0.x; av[1] = (_Float16)v0.y;
                av[2] = (_Float16)v0.z; av[3] = (_Float16)v0.w;
                av[4] = (_Float16)v1.x; av[5] = (_Float16)v1.y;
                av[6] = (_Float16)v1.z; av[7] = (_Float16)v1.w;
            } else {
                av = *(const frag_ab*)(Ah + (size_t)gm * K + k0 + scol);
            }
        } else {
#pragma unroll
            for (int j = 0; j < 8; j++) av[j] = (_Float16)0.f;
        }
        *(frag_ab*)&As[srow * LDK + scol] = av;
        *(frag_ab*)&Bs[srow * LDK + scol] =
            *(const frag_ab*)(BT + (size_t)(bn + srow) * K + k0 + scol);
        *(frag_ab*)&Bs[(64 + srow) * LDK + scol] =
            *(const frag_ab*)(BT + (size_t)(bn + 64 + srow) * K + k0 + scol);
        __syncthreads();
        frag_ab a = *(frag_ab*)&As[(wave * 16 + ml) * LDK + q * 8];
#pragma unroll
        for (int f = 0; f < 8; f++) {
            frag_ab b = *(frag_ab*)&Bs[(f * 16 + ml) * LDK + q * 8];
            acc[f] = __builtin_amdgcn_mfma_f32_16x16x32_f16(a, b, acc[f], 0, 0, 0);
        }
        __syncthreads();
    }
    float asum[4] = {}, dsum[4] = {};
#pragma unroll
    for (int f = 0; f < 8; f++) {
        int cl = f * 16 + ml;
        int col = bn + cl;
        float sa = a_src[head * 128 + cl];
        float da = a_dst[head * 128 + cl];
#pragma unroll
        for (int r = 0; r < 4; r++) {
            int row = bm + wave * 16 + q * 4 + r;
            if (row < Nn) C[(size_t)row * (NH * 128) + col] = (_Float16)acc[f][r];
            asum[r] += acc[f][r] * sa;
            dsum[r] += acc[f][r] * da;
        }
    }
#pragma unroll
    for (int r = 0; r < 4; r++) {
#pragma unroll
        for (int off = 1; off < 16; off <<= 1) {
            asum[r] += __shfl_xor(asum[r], off);
            dsum[r] += __shfl_xor(dsum[r], off);
        }
    }
    if (ml == 0) {
#pragma unroll
        for (int r = 0; r < 4; r++) {
            int row = bm + wave * 16 + q * 4 + r;
            if (row < Nn) {
                as_out[(size_t)head * Nn + row] = asum[r];
                ad_out[(size_t)head * Nn + row] = dsum[r];
            }
        }
    }
}

// ---------------- fused softmax + aggregation (quarter-wave per node, head-sliced) ----------------
template <int LAYER>
static __device__ void pass_body(int vb, const int* __restrict__ counts,
                                 const int* __restrict__ csr,
                                 const float* __restrict__ as,
                                 const float* __restrict__ ad,
                                 const _Float16* __restrict__ hh,
                                 const float* __restrict__ b1,
                                 _Float16* __restrict__ outp, int2 (*ew)[84]) {
    int head = vb & 3;
    int qw = threadIdx.x >> 4;
    int l = threadIdx.x & 15;
    int n = (vb >> 2) * 16 + qw;
    int deg = counts[n]; if (deg > STRIDE) deg = STRIDE;
    int pdeg = (deg + 7) & ~7;
    const float* ash = as + (size_t)head * Nn;
    float adh = ad[(size_t)head * Nn + n];
    int base = n * STRIDE;
    float m = -1e30f;
    for (int k = l; k < pdeg; k += 16) {
        int src = 0; float v = -1e30f;
        if (k < deg) {
            src = csr[base + k];
            v = lrelu(ash[src] + adh);
        }
        ew[qw][k] = make_int2(src, __float_as_int(v));
        m = fmaxf(m, v);
    }
    m = fmaxf(m, __shfl_xor(m, 1));
    m = fmaxf(m, __shfl_xor(m, 2));
    m = fmaxf(m, __shfl_xor(m, 4));
    m = fmaxf(m, __shfl_xor(m, 8));
    float s = 0.f;
    for (int k = l; k < pdeg; k += 16) {
        float e = __expf(__int_as_float(ew[qw][k].y) - m);
        ew[qw][k].y = __float_as_int(e);
        s += e;
    }
    s += __shfl_xor(s, 1);
    s += __shfl_xor(s, 2);
    s += __shfl_xor(s, 4);
    s += __shfl_xor(s, 8);
    float inv = 1.f / (s + 1e-16f);
    int c = head * 128 + (l << 3);
    float acc[8] = {};
    for (int kk = 0; kk < pdeg; kk += 8) {
        int2 pj[8];
#pragma unroll
        for (int j = 0; j < 8; j++) pj[j] = ew[qw][kk + j];
#pragma unroll
        for (int j = 0; j < 8; j++) {
            float w = __int_as_float(pj[j].y);
            frag_ab r = *(const frag_ab*)(hh + (size_t)pj[j].x * 512 + c);
#pragma unroll
            for (int u = 0; u < 8; u++) acc[u] = fmaf((float)r[u], w, acc[u]);
        }
    }
    _Float16 oh[8];
    if constexpr (LAYER == 1) {
#pragma unroll
        for (int j = 0; j < 8; j++)
            oh[j] = (_Float16)fmaxf(acc[j] * inv + b1[c + j], 0.f);
    } else {
        float qq = 0.25f * inv;
#pragma unroll
        for (int j = 0; j < 8; j++) oh[j] = (_Float16)(acc[j] * qq);
    }
    *(float4*)&outp[(size_t)n * 512 + c] = *(float4*)oh;
}

// ---------------- final head-sum + bias ----------------
static __device__ void reduce_out(const Params& p) {
    int gt = blockIdx.x * NT + threadIdx.x;
    for (int i = gt; i < Nn * OUTC; i += GT) {
        int n = i >> 7, oc = i & 127;
        const _Float16* tp = p.tmp + (size_t)n * 512 + oc;
        p.out[i] = (float)tp[0] + (float)tp[128] + (float)tp[256] + (float)tp[384] + p.b2[oc];
    }
}

// ---------------- the whole pipeline as ONE kernel with manual grid barriers ----------------
__global__ __launch_bounds__(NT, 4) void mega(Params p) {
    __shared__ _Float16 As[64 * LDK];
    __shared__ _Float16 Bs[128 * LDK];
    __shared__ int2 ew[16][84];

    // P0: counts=0, weight transposes
    prep0(p);
    gbar(p.bar, 0);

    // P1: gemm1 (fp32 A staged->fp16) on blocks [0,628) || ELL scatter on [628,1024)
    if (blockIdx.x < GEMM_TILES)
        gemm_tile<true>(nullptr, p.x, p.w1t, p.hh, p.a_src1, p.a_dst1, p.as1, p.ad1,
                        INF_, blockIdx.x % MT, blockIdx.x / MT, As, Bs);
    else
        scatter_edges(p, blockIdx.x - GEMM_TILES, GRID - GEMM_TILES);
    gbar(p.bar, 1);

    // P2: softmax+aggregate layer 1 (head = vb&3 constant per block -> XCD L2 slice)
    for (int vb = blockIdx.x; vb < PASS_VB; vb += GRID)
        pass_body<1>(vb, p.counts, p.csr, p.as1, p.ad1, p.hh, p.b1, p.aggh, ew);
    gbar(p.bar, 2);

    // P3: gemm2
    if (blockIdx.x < GEMM_TILES)
        gemm_tile<false>(p.aggh, nullptr, p.w2t, p.hh, p.a_src2, p.a_dst2, p.as2, p.ad2,
                         F1, blockIdx.x % MT, blockIdx.x / MT, As, Bs);
    gbar(p.bar, 3);

    // P4: softmax+aggregate layer 2
    for (int vb = blockIdx.x; vb < PASS_VB; vb += GRID)
        pass_body<2>(vb, p.counts, p.csr, p.as2, p.ad2, p.hh, nullptr, p.tmp, ew);
    gbar(p.bar, 4);

    // P5: head-sum + bias
    reduce_out(p);
}

// ---------------- fallback (plain launches, no barriers) ----------------
__global__ __launch_bounds__(NT) void k_p0(Params p) { prep0(p); }
__global__ __launch_bounds__(NT) void k_p1(Params p) {
    __shared__ _Float16 As[64 * LDK];
    __shared__ _Float16 Bs[128 * LDK];
    if (blockIdx.x < GEMM_TILES)
        gemm_tile<true>(nullptr, p.x, p.w1t, p.hh, p.a_src1, p.a_dst1, p.as1, p.ad1,
                        INF_, blockIdx.x % MT, blockIdx.x / MT, As, Bs);
    else
        scatter_edges(p, blockIdx.x - GEMM_TILES, GRID - GEMM_TILES);
}
__global__ __launch_bounds__(NT) void k_p2(Params p) {
    __shared__ int2 ew[16][84];
    for (int vb = blockIdx.x; vb < PASS_VB; vb += GRID)
        pass_body<1>(vb, p.counts, p.csr, p.as1, p.ad1, p.hh, p.b1, p.aggh, ew);
}
__global__ __launch_bounds__(NT) void k_p3(Params p) {
    __shared__ _Float16 As[64 * LDK];
    __shared__ _Float16 Bs[128 * LDK];
    if (blockIdx.x < GEMM_TILES)
        gemm_tile<false>(p.aggh, nullptr, p.w2t, p.hh, p.a_src2, p.a_dst2, p.as2, p.ad2,
                         F1, blockIdx.x % MT, blockIdx.x / MT, As, Bs);
}
__global__ __launch_bounds__(NT) void k_p4(Params p) {
    __shared__ int2 ew[16][84];
    for (int vb = blockIdx.x; vb < PASS_VB; vb += GRID)
        pass_body<2>(vb, p.counts, p.csr, p.as2, p.ad2, p.hh, nullptr, p.tmp, ew);
}
__global__ __launch_bounds__(NT) void k_p5(Params p) { reduce_out(p); }

extern "C" void kernel_launch(void* const* d_in, const int* in_sizes, int n_in,
                              void* d_out, int out_size, void* d_ws, size_t ws_size,
                              hipStream_t stream) {
    Params p;
    p.x      = (const float*)d_in[0];
    p.ei     = (const int*)d_in[1];
    p.W1     = (const float*)d_in[2];
    p.a_src1 = (const float*)d_in[3];
    p.a_dst1 = (const float*)d_in[4];
    p.b1     = (const float*)d_in[5];
    p.W2     = (const float*)d_in[6];
    p.a_src2 = (const float*)d_in[7];
    p.a_dst2 = (const float*)d_in[8];
    p.b2     = (const float*)d_in[9];
    p.out    = (float*)d_out;

    char* w = (char*)d_ws;
    p.tmp  = (_Float16*)w; w += (size_t)Nn * F2 * 2;
    p.hh   = (_Float16*)w; w += (size_t)Nn * F1 * 2;
    p.aggh = (_Float16*)w; w += (size_t)Nn * F1 * 2;
    p.w1t  = (_Float16*)w; w += (size_t)F1 * INF_ * 2;
    p.w2t  = (_Float16*)w; w += (size_t)F2 * F1 * 2;
    p.as1  = (float*)w;    w += (size_t)NH * Nn * 4;
    p.ad1  = (float*)w;    w += (size_t)NH * Nn * 4;
    p.as2  = (float*)w;    w += (size_t)NH * Nn * 4;
    p.ad2  = (float*)w;    w += (size_t)NH * Nn * 4;
    p.csr  = (int*)w;      w += (size_t)Nn * STRIDE * 4;
    p.counts = (int*)w;    w += (size_t)Nn * 4;
    p.bar  = (int*)w;      w += 8 * 4;

    // Gate the mega path on actual occupancy: barrier is deadlock-free only if
    // all GRID blocks are co-resident (needs >= 4 blocks/CU on 256 CUs).
    static int occ = -1;
    if (occ < 0) {
        int nb = 0;
        if (hipOccupancyMaxActiveBlocksPerMultiprocessor(&nb, mega, NT, 0) != hipSuccess)
            nb = 0;
        occ = nb;
    }

    if (occ >= 4) {
        (void)hipMemsetAsync(p.bar, 0, 8 * sizeof(int), stream);   // zero barrier counters
        mega<<<GRID, NT, 0, stream>>>(p);
    } else {
        k_p0<<<GRID, NT, 0, stream>>>(p);
        k_p1<<<GRID, NT, 0, stream>>>(p);
        k_p2<<<GRID, NT, 0, stream>>>(p);
        k_p3<<<GEMM_TILES, NT, 0, stream>>>(p);
        k_p4<<<GRID, NT, 0, stream>>>(p);
        k_p5<<<GRID, NT, 0, stream>>>(p);
    }
}